// Round 5
// baseline (113.676 us; speedup 1.0000x reference)
//
#include <hip/hip_runtime.h>
#include <math.h>

#define BDIM 4
#define NDIM 4096
#define MDIM 4096
#define CDIM 128
#define KSEL 32
#define NCELL 64     // 4x4x4 grid, cell 0.25 >= 2*r widened => ball spans <=2 cells/dim
#define CAP 128      // per-wave candidate cap (expected ~30 hits; P(>128) ~ 0)
#define WPB 8        // waves (anchors) per block: 512-thread blocks fill the
                     // 32-wave/CU budget with only 4 workgroup slots (R11 fix
                     // for the persistent ~45% occupancy = wg-slot limit)

typedef float v2f __attribute__((ext_vector_type(2)));

// ws layout:
//   pre[7*C] f32        @ 0
//   starts[65*B] i32    @ STARTS_OFF
//   cnts_blk[64*64] i32 @ CNTSB_OFF   (per count-block histograms)
//   ready[64] i32       @ READY_OFF
//   go i32 (+pad)       @ GO_OFF
//   curs[B*64] i32      @ CURS_OFF
//   pts4[B*M] float4    @ PTS4_OFF
#define PRE_BYTES (7 * CDIM * 4)                        // 3584
#define STARTS_OFF PRE_BYTES
#define STARTS_BYTES ((NCELL + 1) * BDIM * 4)           // 1040
#define CNTSB_OFF (STARTS_OFF + STARTS_BYTES)           // 4624
#define CNTSB_BYTES (64 * NCELL * 4)                    // 16384
#define READY_OFF (CNTSB_OFF + CNTSB_BYTES)             // 21008
#define READY_BYTES (64 * 4)                            // 256
#define GO_OFF (READY_OFF + READY_BYTES)                // 21264
#define GO_BYTES 16
#define CURS_OFF (GO_OFF + GO_BYTES)                    // 21280
#define CURS_BYTES (BDIM * NCELL * 4)                   // 1024
#define PTS4_OFF (CURS_OFF + CURS_BYTES)                // 22304 (16B aligned)
#define WS_NEEDED (PTS4_OFF + (size_t)BDIM * MDIM * 16)

// distinct-byte magics: cannot equal any repeated-byte poison fill pattern
#define MAGIC_RDY 0x3A7C19E5
#define MAGIC_GO  0x5D2B8F41

// ---------------------------------------------------------------------------
// helpers
// ---------------------------------------------------------------------------
__device__ __forceinline__ float exp2_hw(float x) {   // bare v_exp_f32 (~1 ulp)
    float r;
    asm("v_exp_f32 %0, %1" : "=v"(r) : "v"(x));
    return r;
}

template <int CTRL, int MASK>
__device__ __forceinline__ float dpp_add(float x) {   // VALU-pipe reduction step
    const int r = __builtin_amdgcn_update_dpp(0, __float_as_int(x), CTRL, MASK, 0xF, true);
    return x + __int_as_float(r);
}
#define DPP_QUAD_XOR1 0xB1
#define DPP_QUAD_XOR2 0x4E
#define DPP_ROW_HALF_MIRROR 0x141
#define DPP_ROW_MIRROR      0x140
#define DPP_ROW_BCAST15     0x142
#define DPP_ROW_BCAST31     0x143

// # set bits of mk in lanes strictly below this lane (v_mbcnt_lo+hi)
__device__ __forceinline__ int rank_before(unsigned long long mk) {
    return __builtin_amdgcn_mbcnt_hi((unsigned)(mk >> 32),
                                     __builtin_amdgcn_mbcnt_lo((unsigned)mk, 0));
}

__device__ __forceinline__ int cell_of(float v) {
    int c = (int)(v * 4.0f);
    return c < 0 ? 0 : (c > 3 ? 3 : c);
}

__device__ __forceinline__ v2f splat(float x) { v2f r; r.x = x; r.y = x; return r; }

// packed fma: lowers to v_pk_fma_f32 (full-rate, 2 fp32 FMA / inst)
__device__ __forceinline__ v2f pk_fma(v2f a, v2f b, v2f c) {
    return __builtin_elementwise_fma(a, b, c);
}

// per-lane channel-pair weights (2 channels per lane)
struct LaneW {
    v2f wqa0, wqa1, wqa2;   // (Wq@Wa)*log2e
    v2f nka0, nka1, nka2;   // -(Wk@Wa)*log2e  (pre-negated)
    v2f cav;                // ((bq-bk)@Wa+ba)*log2e
    v2f wd0, wd1, wd2, bdv; // raw Wd rows + bd
};

__device__ __forceinline__ void load_lane_weights(LaneW& P, const float* pre,
                                                  const float* Wd, const float* bd, int lane) {
    const v2f* pre2 = (const v2f*)pre;
    const v2f* wdp  = (const v2f*)Wd;
    const v2f* bdp  = (const v2f*)bd;
    P.wqa0 = pre2[0 * 64 + lane]; P.wqa1 = pre2[1 * 64 + lane]; P.wqa2 = pre2[2 * 64 + lane];
    P.nka0 = pre2[3 * 64 + lane]; P.nka1 = pre2[4 * 64 + lane]; P.nka2 = pre2[5 * 64 + lane];
    P.cav  = pre2[6 * 64 + lane];
    P.wd0 = wdp[0 * 64 + lane]; P.wd1 = wdp[1 * 64 + lane]; P.wd2 = wdp[2 * 64 + lane];
    P.bdv = bdp[lane];
}

// ---------------------------------------------------------------------------
// fp64 folded-weight fold, work item i in [0, 7*128)  (numerics unchanged)
// ---------------------------------------------------------------------------
__device__ __forceinline__ void fold_one(int i, const float* Wq, const float* bq,
                                         const float* Wk, const float* bk,
                                         const float* Wa, const float* ba,
                                         float* pre) {
    const double LOG2E = 1.4426950408889634074;
    const int r = i >> 7, c = i & (CDIM - 1);
    if (r < 3) {
        double s0 = 0, s1 = 0, s2 = 0, s3 = 0;
        for (int k = 0; k < CDIM; k += 4) {
            s0 += (double)Wq[r * CDIM + k + 0] * (double)Wa[(k + 0) * CDIM + c];
            s1 += (double)Wq[r * CDIM + k + 1] * (double)Wa[(k + 1) * CDIM + c];
            s2 += (double)Wq[r * CDIM + k + 2] * (double)Wa[(k + 2) * CDIM + c];
            s3 += (double)Wq[r * CDIM + k + 3] * (double)Wa[(k + 3) * CDIM + c];
        }
        pre[r * CDIM + c] = (float)(((s0 + s1) + (s2 + s3)) * LOG2E);
    } else if (r < 6) {
        const int rr = r - 3;
        double s0 = 0, s1 = 0, s2 = 0, s3 = 0;
        for (int k = 0; k < CDIM; k += 4) {
            s0 += (double)Wk[rr * CDIM + k + 0] * (double)Wa[(k + 0) * CDIM + c];
            s1 += (double)Wk[rr * CDIM + k + 1] * (double)Wa[(k + 1) * CDIM + c];
            s2 += (double)Wk[rr * CDIM + k + 2] * (double)Wa[(k + 2) * CDIM + c];
            s3 += (double)Wk[rr * CDIM + k + 3] * (double)Wa[(k + 3) * CDIM + c];
        }
        pre[r * CDIM + c] = (float)(((s0 + s1) + (s2 + s3)) * (-LOG2E));  // negated
    } else {
        double s = (double)ba[c];
        for (int k = 0; k < CDIM; ++k)
            s += ((double)bq[k] - (double)bk[k]) * (double)Wa[k * CDIM + c];
        pre[6 * CDIM + c] = (float)(s * LOG2E);
    }
}

// ---------------------------------------------------------------------------
// R10 parallel setup — ONE dispatch, 69 blocks x 256 (all co-resident).
// ---------------------------------------------------------------------------
#define SETUP_BLOCKS 69

__launch_bounds__(256)
__global__ void setup2_kernel(const float* __restrict__ neighbor,
                              const float* __restrict__ Wq, const float* __restrict__ bq,
                              const float* __restrict__ Wk, const float* __restrict__ bk,
                              const float* __restrict__ Wa, const float* __restrict__ ba,
                              float* __restrict__ pre,
                              int* __restrict__ starts,
                              int* __restrict__ cnts_blk,
                              int* __restrict__ ready,
                              int* __restrict__ go,
                              int* __restrict__ curs,
                              float4* __restrict__ pts4) {
    const int blk = blockIdx.x;
    const int t = threadIdx.x;

    if (blk < 64) {
        // ---- count phase ----
        __shared__ int hist[NCELL];
        __shared__ int base_sh[NCELL];
        const int b = blk >> 4;
        const int i = ((blk & 15) << 8) + t;          // 256 points per block
        if (t < NCELL) hist[t] = 0;
        __syncthreads();
        const float* p = neighbor + ((size_t)b * MDIM + i) * 3;
        const float x = p[0], y = p[1], z = p[2];
        const int cell = (cell_of(z) * 4 + cell_of(y)) * 4 + cell_of(x);
        const int myrank = atomicAdd(&hist[cell], 1);  // per-block per-cell rank
        __syncthreads();
        if (t < NCELL)
            __hip_atomic_store(&cnts_blk[blk * NCELL + t], hist[t],
                               __ATOMIC_RELAXED, __HIP_MEMORY_SCOPE_AGENT);
        __syncthreads();   // all publishes done (waitcnt) before flag
        if (t == 0)
            __hip_atomic_store(&ready[blk], MAGIC_RDY,
                               __ATOMIC_RELEASE, __HIP_MEMORY_SCOPE_AGENT);
        // ---- wait for scan ----
        if (t == 0) {
            while (__hip_atomic_load(go, __ATOMIC_ACQUIRE,
                                     __HIP_MEMORY_SCOPE_AGENT) != MAGIC_GO)
                __builtin_amdgcn_s_sleep(8);
        }
        __syncthreads();
        // ---- scatter phase: block-level reservation then ordered fill ----
        if (t < NCELL) {
            const int h = hist[t];
            base_sh[t] = h ? atomicAdd(&curs[b * NCELL + t], h) : 0;
        }
        __syncthreads();
        const int slot = base_sh[cell] + myrank;
        pts4[(size_t)b * MDIM + slot] = make_float4(x, y, z, __int_as_float(i));
    } else if (blk < 68) {
        // ---- fold phase on 4 CUs ----
        const int idx = (blk - 64) * 256 + t;
        if (idx < 7 * CDIM) fold_one(idx, Wq, bq, Wk, bk, Wa, ba, pre);
    } else {
        // ---- scan block ----
        const int lane = t & 63;
        if (t < 64) {   // wave 0: poll all 64 ready flags, one per lane
            while (!__all(__hip_atomic_load(&ready[lane], __ATOMIC_ACQUIRE,
                                            __HIP_MEMORY_SCOPE_AGENT) == MAGIC_RDY))
                __builtin_amdgcn_s_sleep(8);
        }
        __syncthreads();
        const int b = t >> 6;           // wave w handles batch w
        int v = 0;
        #pragma unroll
        for (int j = 0; j < 16; ++j)
            v += __hip_atomic_load(&cnts_blk[(b * 16 + j) * NCELL + lane],
                                   __ATOMIC_RELAXED, __HIP_MEMORY_SCOPE_AGENT);
        int inc = v;
        #pragma unroll
        for (int off = 1; off < 64; off <<= 1) {
            const int u = __shfl_up(inc, off);
            if (lane >= off) inc += u;
        }
        const int excl = inc - v;
        starts[b * (NCELL + 1) + lane] = excl;            // consumed post-boundary
        if (lane == NCELL - 1) starts[b * (NCELL + 1) + NCELL] = inc;
        __hip_atomic_store(&curs[b * NCELL + lane], excl,
                           __ATOMIC_RELAXED, __HIP_MEMORY_SCOPE_AGENT);
        __syncthreads();   // all curs stores complete
        if (t == 0)
            __hip_atomic_store(go, MAGIC_GO,
                               __ATOMIC_RELEASE, __HIP_MEMORY_SCOPE_AGENT);
    }
}

// ---------------------------------------------------------------------------
// Legacy fold-only setup — kept for the small-ws fallback path.
// ---------------------------------------------------------------------------
__launch_bounds__(1024)
__global__ void setup_kernel(const float* __restrict__ Wq, const float* __restrict__ bq,
                             const float* __restrict__ Wk, const float* __restrict__ bk,
                             const float* __restrict__ Wa, const float* __restrict__ ba,
                             float* __restrict__ pre) {
    const int t = threadIdx.x;
    if (t < 7 * CDIM) fold_one(t, Wq, bq, Wk, bk, Wa, ba, pre);
}

// ---------------------------------------------------------------------------
// Main kernel: 1 wave per anchor, WPB=8 independent waves / 512-thread block.
// R11: 512-thread blocks — the stuck ~45% occupancy across R0-R10 matches a
//      per-CU workgroup-slot limit (~4 blocks/CU x 4 waves = 16 of 32 waves).
//      8 waves/block fills 32 waves/CU with 4 slots. Phase-2 padding replaced
//      by bulk-8 groups + one clamped tail group (idx=min(j+t,eff-1); dup
//      points idempotent under min, identical denominators) — removes the
//      mult-8 pad waste R9 introduced.
// ---------------------------------------------------------------------------
__launch_bounds__(512)
__global__ void attn2_kernel(const float* __restrict__ anchor,
                             const float* __restrict__ neighbor,
                             const float* __restrict__ Wd,
                             const float* __restrict__ bd,
                             const float* __restrict__ pre,
                             const float4* __restrict__ pts4,
                             const int* __restrict__ starts,
                             float* __restrict__ out) {
    __shared__ float4 cand[WPB][CAP - KSEL];
    __shared__ float4 sel[WPB][KSEL];

    const int b    = blockIdx.x >> 9;              // 512 blocks per batch
    const int n0   = (blockIdx.x & 511) << 3;      // 8 anchors per block
    const int tid  = threadIdx.x;
    const int w    = tid >> 6;
    const int lane = tid & 63;

    const int n = n0 + w;
    const float* ap = anchor + ((size_t)b * NDIM + n) * 3;
    const float ax = ap[0], ay = ap[1], az = ap[2];
    const float* nbb = neighbor + (size_t)b * MDIM * 3;

    LaneW P;
    load_lane_weights(P, pre, Wd, bd, lane);

    const v2f axv = splat(ax), ayv = splat(ay), azv = splat(az);
    const v2f qa  = pk_fma(axv, P.wqa0, pk_fma(ayv, P.wqa1, pk_fma(azv, P.wqa2, P.cav)));
    const v2f ad  = pk_fma(axv, P.wd0, pk_fma(ayv, P.wd1, pk_fma(azv, P.wd2, P.bdv)));
    const v2f nad = -ad;   // phase 2 computes m = p·Wd − ad = −dis

    // --- phase 1: binned candidate collection ---
    constexpr float R2 = (float)(0.12 * 0.12);
    const float RP = 0.1201f;   // widened; 2*RP < 0.25 => <=2 cells/dim always

    const int cx0 = max(0, (int)((ax - RP) * 4.0f)), cx1 = min(3, (int)((ax + RP) * 4.0f));
    const int cy0 = max(0, (int)((ay - RP) * 4.0f)), cy1 = min(3, (int)((ay + RP) * 4.0f));
    const int cz0 = max(0, (int)((az - RP) * 4.0f)), cz1 = min(3, (int)((az + RP) * 4.0f));

    const float4* pb = pts4 + (size_t)b * MDIM;
    const int* st = starts + b * (NCELL + 1);

    // static 2x2 row enumeration (span <= 2 cells/dim always); all 8 loads
    // issue in parallel, duplicate rows are emptied via re=rs.
    const int r00 = (cz0 * 4 + cy0) * 4, r01 = (cz0 * 4 + cy1) * 4;
    const int r10 = (cz1 * 4 + cy0) * 4, r11 = (cz1 * 4 + cy1) * 4;
    int rs0 = st[r00 + cx0], re0 = st[r00 + cx1 + 1];
    int rs1 = st[r01 + cx0], re1 = st[r01 + cx1 + 1];
    int rs2 = st[r10 + cx0], re2 = st[r10 + cx1 + 1];
    int rs3 = st[r11 + cx0], re3 = st[r11 + cx1 + 1];
    const bool vy = cy1 > cy0, vz = cz1 > cz0;
    if (!vy) re1 = rs1;                       // row01 duplicates row00
    if (!vz) { re2 = rs2; re3 = rs3; }        // row1x duplicate row0x
    else if (!vy) re3 = rs3;                  // row11 duplicates row10

    int cnt = 0;
    auto scan_range = [&](int beg, int end) {
        if (beg >= end) return;
        float4 p = pb[min(beg + lane, end - 1)];
        for (int base = beg; base < end; base += 64) {
            // branchless prefetch of the next tile (clamped; harmless dup read
            // on the last iteration).
            float4 pn = pb[min(base + 64 + lane, end - 1)];
            const int i = base + lane;
            const float dx = __fsub_rn(ax, p.x);
            const float dy = __fsub_rn(ay, p.y);
            const float dz = __fsub_rn(az, p.z);
            const float d2 = __fadd_rn(__fadd_rn(__fmul_rn(dx, dx), __fmul_rn(dy, dy)),
                                       __fmul_rn(dz, dz));
            const bool in = (i < end) && (d2 < R2);
            const unsigned long long mk = __ballot(in);
            const int pos = cnt + rank_before(mk);
            if (in && pos < CAP) {
                if (pos < KSEL) sel[w][pos] = p;
                else            cand[w][pos - KSEL] = p;
            }
            cnt += __popcll(mk);
            p = pn;
        }
    };
    scan_range(rs0, re0);
    scan_range(rs1, re1);
    scan_range(rs2, re2);
    scan_range(rs3, re3);

    // --- selection: the K smallest original indices among hits ---
    int eff;
    if (cnt == 0) {
        if (lane == 0) sel[w][0] = make_float4(nbb[0], nbb[1], nbb[2], 0.0f);
        eff = 1;
    } else if (cnt <= KSEL) {
        eff = cnt;                       // sel already holds them, in hit order
    } else if (cnt <= CAP) {
        // gather hit h for this lane: h<KSEL -> sel[h], else cand[h-KSEL]
        float4 c0v = make_float4(0, 0, 0, 0), c1v = make_float4(0, 0, 0, 0);
        int i0 = 0x7fffffff, i1 = 0x7fffffff;
        if (lane < cnt) {
            c0v = (lane < KSEL) ? sel[w][lane] : cand[w][lane - KSEL];
            i0 = __float_as_int(c0v.w);
        }
        if (lane + 64 < cnt) {
            c1v = cand[w][lane + 64 - KSEL];
            i1 = __float_as_int(c1v.w);
        }
        int lo = 0, hi = MDIM - 1;   // smallest T with count(idx<=T) >= KSEL
        while (lo < hi) {
            const int mid = (lo + hi) >> 1;
            const int c = __popcll(__ballot(i0 <= mid)) + __popcll(__ballot(i1 <= mid));
            if (c >= KSEL) hi = mid; else lo = mid + 1;
        }
        __builtin_amdgcn_wave_barrier();   // reads above complete before sel rewrite
        const bool k0 = (i0 <= lo);
        const unsigned long long m0 = __ballot(k0);
        if (k0) sel[w][rank_before(m0)] = c0v;
        const int cc0 = __popcll(m0);
        const bool k1 = (i1 <= lo);
        const unsigned long long m1 = __ballot(k1);
        if (k1) sel[w][cc0 + rank_before(m1)] = c1v;
        eff = KSEL;
    } else {
        // overflow fallback (statistically never): ordered full scan, first K
        int c2 = 0;
        for (int base = 0; base < MDIM && c2 < KSEL; base += 64) {
            const int m = base + lane;
            const float* p = nbb + 3 * m;
            const float nx = p[0], ny = p[1], nz = p[2];
            const float dx = __fsub_rn(ax, nx);
            const float dy = __fsub_rn(ay, ny);
            const float dz = __fsub_rn(az, nz);
            const float d2 = __fadd_rn(__fadd_rn(__fmul_rn(dx, dx), __fmul_rn(dy, dy)),
                                       __fmul_rn(dz, dz));
            const bool in = d2 < R2;
            const unsigned long long mk = __ballot(in);
            const int pos = c2 + rank_before(mk);
            if (in && pos < KSEL) sel[w][pos] = make_float4(nx, ny, nz, 0.0f);
            c2 += __popcll(mk);
        }
        eff = KSEL;
    }

    __builtin_amdgcn_wave_barrier();
    __builtin_amdgcn_s_waitcnt(0);   // sel writes visible to this wave's reads

    // --- phase 2: packed channel softmax (exp2 domain) + min-accumulate of
    //     m·e/S where m = −dis; output negated at the store. Bulk groups of 8
    //     (no clamp), then one clamped tail group of 4 or 8 (dup of last
    //     point: idempotent under min, same denominator). ---
    v2f acc = splat(1e30f);

    auto group = [&](int j, int G, bool clamp) {
        v2f pr[8];
        float sv[8];
        for (int t = 0; t < G; ++t) {
            const int idx = clamp ? min(j + t, eff - 1) : (j + t);
            const float4 v = sel[w][idx];
            const v2f vx = splat(v.x), vy2 = splat(v.y), vz2 = splat(v.z);
            const v2f l = pk_fma(vx, P.nka0, pk_fma(vy2, P.nka1, pk_fma(vz2, P.nka2, qa)));
            v2f e; e.x = exp2_hw(l.x); e.y = exp2_hw(l.y);
            sv[t] = e.x + e.y;
            const v2f m = pk_fma(vx, P.wd0, pk_fma(vy2, P.wd1, pk_fma(vz2, P.wd2, nad)));
            pr[t] = m * e;   // v_pk_mul_f32 (= −dis·e)
        }
        for (int t = 0; t < G; ++t) sv[t] = dpp_add<DPP_QUAD_XOR1, 0xF>(sv[t]);
        for (int t = 0; t < G; ++t) sv[t] = dpp_add<DPP_QUAD_XOR2, 0xF>(sv[t]);
        for (int t = 0; t < G; ++t) sv[t] = dpp_add<DPP_ROW_HALF_MIRROR, 0xF>(sv[t]);
        for (int t = 0; t < G; ++t) sv[t] = dpp_add<DPP_ROW_MIRROR, 0xF>(sv[t]);
        for (int t = 0; t < G; ++t) sv[t] = dpp_add<DPP_ROW_BCAST15, 0xA>(sv[t]);
        for (int t = 0; t < G; ++t) sv[t] = dpp_add<DPP_ROW_BCAST31, 0xC>(sv[t]);
        for (int t = 0; t < G; ++t) {
            const float tot = __int_as_float(__builtin_amdgcn_readlane(__float_as_int(sv[t]), 63));
            const v2f iv = splat(__builtin_amdgcn_rcpf(tot));
            acc = __builtin_elementwise_min(acc, pr[t] * iv);   // pk_mul + pk_min
        }
    };

    int j = 0;
    for (; j + 8 <= eff; j += 8) group(j, 8, false);
    const int rem = eff - j;
    if (rem > 0) {
        if (rem <= 4) group(j, 4, true);
        else          group(j, 8, true);
    }

    float2 o; o.x = -acc.x; o.y = -acc.y;
    ((float2*)out)[((size_t)b * NDIM + n) * 64 + lane] = o;
}

// ---------------------------------------------------------------------------
// Fallback (ws too small for bins): full-scan kernel (ordered early-exit).
// ---------------------------------------------------------------------------
__launch_bounds__(256)
__global__ void attn_fallback(const float* __restrict__ anchor,
                              const float* __restrict__ neighbor,
                              const float* __restrict__ Wd,
                              const float* __restrict__ bd,
                              const float* __restrict__ pre,
                              float* __restrict__ out) {
    __shared__ float4 sel[4][KSEL];
    __shared__ int lists[4][KSEL];

    const int b = blockIdx.x >> 10, n0 = (blockIdx.x & 1023) << 2;
    const int tid = threadIdx.x, w = tid >> 6, lane = tid & 63;
    const int n = n0 + w;
    const float* ap = anchor + ((size_t)b * NDIM + n) * 3;
    const float ax = ap[0], ay = ap[1], az = ap[2];
    const float* nbb = neighbor + (size_t)b * MDIM * 3;

    LaneW P;
    load_lane_weights(P, pre, Wd, bd, lane);
    const v2f axv = splat(ax), ayv = splat(ay), azv = splat(az);
    const v2f qa = pk_fma(axv, P.wqa0, pk_fma(ayv, P.wqa1, pk_fma(azv, P.wqa2, P.cav)));
    const v2f ad = pk_fma(axv, P.wd0, pk_fma(ayv, P.wd1, pk_fma(azv, P.wd2, P.bdv)));
    const v2f nwd0 = -P.wd0, nwd1 = -P.wd1, nwd2 = -P.wd2;

    constexpr float R2 = (float)(0.12 * 0.12);
    int cnt = 0;
    for (int base = 0; base < MDIM && cnt < KSEL; base += 64) {
        const int m = base + lane;
        const float* p = nbb + 3 * m;
        const float dx = __fsub_rn(ax, p[0]);
        const float dy = __fsub_rn(ay, p[1]);
        const float dz = __fsub_rn(az, p[2]);
        const float d2 = __fadd_rn(__fadd_rn(__fmul_rn(dx, dx), __fmul_rn(dy, dy)),
                                   __fmul_rn(dz, dz));
        const bool in = d2 < R2;
        const unsigned long long mk = __ballot(in);
        const int pos = cnt + rank_before(mk);
        if (in && pos < KSEL) lists[w][pos] = m;
        cnt += __popcll(mk);
    }
    int eff = cnt < KSEL ? cnt : KSEL;
    if (cnt == 0) { if (lane == 0) lists[w][0] = 0; eff = 1; }
    const int eff4 = (eff + 3) & ~3;
    if (lane == 0) for (int j = eff; j < eff4; ++j) lists[w][j] = lists[w][0];
    __builtin_amdgcn_wave_barrier();
    if (lane < eff4) {
        const float* p = nbb + 3 * lists[w][lane];
        sel[w][lane] = make_float4(p[0], p[1], p[2], 0.f);
    }
    __builtin_amdgcn_wave_barrier();

    v2f acc = splat(-1e30f);
    for (int j = 0; j < eff4; j += 4) {
        v2f pr[4]; float sv[4];
        #pragma unroll
        for (int t = 0; t < 4; ++t) {
            const float4 v = sel[w][j + t];
            const v2f vx = splat(v.x), vy = splat(v.y), vz = splat(v.z);
            const v2f l = pk_fma(vx, P.nka0, pk_fma(vy, P.nka1, pk_fma(vz, P.nka2, qa)));
            v2f e; e.x = exp2_hw(l.x); e.y = exp2_hw(l.y);
            sv[t] = e.x + e.y;
            const v2f d = pk_fma(vx, nwd0, pk_fma(vy, nwd1, pk_fma(vz, nwd2, ad)));
            pr[t] = d * e;
        }
        #pragma unroll
        for (int t = 0; t < 4; ++t) sv[t] = dpp_add<DPP_QUAD_XOR1, 0xF>(sv[t]);
        #pragma unroll
        for (int t = 0; t < 4; ++t) sv[t] = dpp_add<DPP_QUAD_XOR2, 0xF>(sv[t]);
        #pragma unroll
        for (int t = 0; t < 4; ++t) sv[t] = dpp_add<DPP_ROW_HALF_MIRROR, 0xF>(sv[t]);
        #pragma unroll
        for (int t = 0; t < 4; ++t) sv[t] = dpp_add<DPP_ROW_MIRROR, 0xF>(sv[t]);
        #pragma unroll
        for (int t = 0; t < 4; ++t) sv[t] = dpp_add<DPP_ROW_BCAST15, 0xA>(sv[t]);
        #pragma unroll
        for (int t = 0; t < 4; ++t) sv[t] = dpp_add<DPP_ROW_BCAST31, 0xC>(sv[t]);
        #pragma unroll
        for (int t = 0; t < 4; ++t) {
            const float tot = __int_as_float(__builtin_amdgcn_readlane(__float_as_int(sv[t]), 63));
            const v2f iv = splat(__builtin_amdgcn_rcpf(tot));
            acc = __builtin_elementwise_max(acc, pr[t] * iv);
        }
    }
    float2 o; o.x = acc.x; o.y = acc.y;
    ((float2*)out)[((size_t)b * NDIM + n) * 64 + lane] = o;
}

extern "C" void kernel_launch(void* const* d_in, const int* in_sizes, int n_in,
                              void* d_out, int out_size, void* d_ws, size_t ws_size,
                              hipStream_t stream) {
    const float* anchor   = (const float*)d_in[0];
    const float* neighbor = (const float*)d_in[1];
    const float* Wq = (const float*)d_in[2];
    const float* bq = (const float*)d_in[3];
    const float* Wk = (const float*)d_in[4];
    const float* bk = (const float*)d_in[5];
    const float* Wd = (const float*)d_in[6];
    const float* bd = (const float*)d_in[7];
    const float* Wa = (const float*)d_in[8];
    const float* ba = (const float*)d_in[9];
    float* out = (float*)d_out;

    float* pre    = (float*)d_ws;
    int* starts   = (int*)((char*)d_ws + STARTS_OFF);
    int* cnts_blk = (int*)((char*)d_ws + CNTSB_OFF);
    int* ready    = (int*)((char*)d_ws + READY_OFF);
    int* go       = (int*)((char*)d_ws + GO_OFF);
    int* curs     = (int*)((char*)d_ws + CURS_OFF);
    float4* pts4  = (float4*)((char*)d_ws + PTS4_OFF);

    if (ws_size >= WS_NEEDED) {
        setup2_kernel<<<dim3(SETUP_BLOCKS), dim3(256), 0, stream>>>(
            neighbor, Wq, bq, Wk, bk, Wa, ba, pre, starts,
            cnts_blk, ready, go, curs, pts4);
        attn2_kernel<<<dim3(BDIM * NDIM / WPB), dim3(64 * WPB), 0, stream>>>(
            anchor, neighbor, Wd, bd, pre, pts4, starts, out);
    } else {
        setup_kernel<<<dim3(1), dim3(1024), 0, stream>>>(
            Wq, bq, Wk, bk, Wa, ba, pre);
        attn_fallback<<<dim3(BDIM * NDIM / 4), dim3(256), 0, stream>>>(
            anchor, neighbor, Wd, bd, pre, out);
    }
}

// Round 7
// 112.493 us; speedup vs baseline: 1.0105x; 1.0105x over previous
//
#include <hip/hip_runtime.h>
#include <math.h>

#define BDIM 4
#define NDIM 4096
#define MDIM 4096
#define CDIM 128
#define KSEL 32
#define NCELL 64     // 4x4x4 grid, cell 0.25 >= 2*r widened => ball spans <=2 cells/dim
#define CAP 128      // per-wave candidate cap (expected ~30 hits; P(>128) ~ 0)
#define WPB 2        // 128-thread blocks -> fine-grained backfill against
                     // per-wave work imbalance (occupancy pinned ~46% across
                     // 256/512-thread configs = imbalance tail, not resources)

typedef float v2f __attribute__((ext_vector_type(2)));

// ws layout:
//   pre[7*C] f32        @ 0
//   starts[65*B] i32    @ STARTS_OFF
//   cnts_blk[64*64] i32 @ CNTSB_OFF   (per count-block histograms)
//   ready[64] i32       @ READY_OFF
//   go i32 (+pad)       @ GO_OFF
//   curs[B*64] i32      @ CURS_OFF
//   pts4[B*M] float4    @ PTS4_OFF
#define PRE_BYTES (7 * CDIM * 4)                        // 3584
#define STARTS_OFF PRE_BYTES
#define STARTS_BYTES ((NCELL + 1) * BDIM * 4)           // 1040
#define CNTSB_OFF (STARTS_OFF + STARTS_BYTES)           // 4624
#define CNTSB_BYTES (64 * NCELL * 4)                    // 16384
#define READY_OFF (CNTSB_OFF + CNTSB_BYTES)             // 21008
#define READY_BYTES (64 * 4)                            // 256
#define GO_OFF (READY_OFF + READY_BYTES)                // 21264
#define GO_BYTES 16
#define CURS_OFF (GO_OFF + GO_BYTES)                    // 21280
#define CURS_BYTES (BDIM * NCELL * 4)                   // 1024
#define PTS4_OFF (CURS_OFF + CURS_BYTES)                // 22304 (16B aligned)
#define WS_NEEDED (PTS4_OFF + (size_t)BDIM * MDIM * 16)

// distinct-byte magics: cannot equal any repeated-byte poison fill pattern
#define MAGIC_RDY 0x3A7C19E5
#define MAGIC_GO  0x5D2B8F41

// ---------------------------------------------------------------------------
// helpers
// ---------------------------------------------------------------------------
__device__ __forceinline__ float exp2_hw(float x) {   // bare v_exp_f32 (~1 ulp)
    float r;
    asm("v_exp_f32 %0, %1" : "=v"(r) : "v"(x));
    return r;
}

// R13 NOTE: inline-asm v_add_f32_dpp (R12) produced WRONG RESULTS — gfx9
// VALU->DPP read hazards are software-managed and the compiler cannot insert
// the required s_nops inside asm blobs. ALWAYS use __builtin_amdgcn_update_dpp
// (compiler-managed hazards), even though it costs a mov per step.
template <int CTRL, int MASK>
__device__ __forceinline__ float dpp_add(float x) {   // VALU-pipe reduction step
    const int r = __builtin_amdgcn_update_dpp(0, __float_as_int(x), CTRL, MASK, 0xF, true);
    return x + __int_as_float(r);
}
#define DPP_QUAD_XOR1 0xB1
#define DPP_QUAD_XOR2 0x4E
#define DPP_ROW_HALF_MIRROR 0x141
#define DPP_ROW_MIRROR      0x140
#define DPP_ROW_BCAST15     0x142
#define DPP_ROW_BCAST31     0x143

// # set bits of mk in lanes strictly below this lane (v_mbcnt_lo+hi)
__device__ __forceinline__ int rank_before(unsigned long long mk) {
    return __builtin_amdgcn_mbcnt_hi((unsigned)(mk >> 32),
                                     __builtin_amdgcn_mbcnt_lo((unsigned)mk, 0));
}

__device__ __forceinline__ int cell_of(float v) {
    int c = (int)(v * 4.0f);
    return c < 0 ? 0 : (c > 3 ? 3 : c);
}

__device__ __forceinline__ v2f splat(float x) { v2f r; r.x = x; r.y = x; return r; }

// packed fma: lowers to v_pk_fma_f32 (full-rate, 2 fp32 FMA / inst)
__device__ __forceinline__ v2f pk_fma(v2f a, v2f b, v2f c) {
    return __builtin_elementwise_fma(a, b, c);
}

// per-lane channel-pair weights (2 channels per lane)
struct LaneW {
    v2f wqa0, wqa1, wqa2;   // (Wq@Wa)*log2e
    v2f nka0, nka1, nka2;   // -(Wk@Wa)*log2e  (pre-negated)
    v2f cav;                // ((bq-bk)@Wa+ba)*log2e
    v2f wd0, wd1, wd2, bdv; // raw Wd rows + bd
};

__device__ __forceinline__ void load_lane_weights(LaneW& P, const float* pre,
                                                  const float* Wd, const float* bd, int lane) {
    const v2f* pre2 = (const v2f*)pre;
    const v2f* wdp  = (const v2f*)Wd;
    const v2f* bdp  = (const v2f*)bd;
    P.wqa0 = pre2[0 * 64 + lane]; P.wqa1 = pre2[1 * 64 + lane]; P.wqa2 = pre2[2 * 64 + lane];
    P.nka0 = pre2[3 * 64 + lane]; P.nka1 = pre2[4 * 64 + lane]; P.nka2 = pre2[5 * 64 + lane];
    P.cav  = pre2[6 * 64 + lane];
    P.wd0 = wdp[0 * 64 + lane]; P.wd1 = wdp[1 * 64 + lane]; P.wd2 = wdp[2 * 64 + lane];
    P.bdv = bdp[lane];
}

// ---------------------------------------------------------------------------
// fp64 folded-weight fold, work item i in [0, 7*128)  (numerics unchanged)
// ---------------------------------------------------------------------------
__device__ __forceinline__ void fold_one(int i, const float* Wq, const float* bq,
                                         const float* Wk, const float* bk,
                                         const float* Wa, const float* ba,
                                         float* pre) {
    const double LOG2E = 1.4426950408889634074;
    const int r = i >> 7, c = i & (CDIM - 1);
    if (r < 3) {
        double s0 = 0, s1 = 0, s2 = 0, s3 = 0;
        for (int k = 0; k < CDIM; k += 4) {
            s0 += (double)Wq[r * CDIM + k + 0] * (double)Wa[(k + 0) * CDIM + c];
            s1 += (double)Wq[r * CDIM + k + 1] * (double)Wa[(k + 1) * CDIM + c];
            s2 += (double)Wq[r * CDIM + k + 2] * (double)Wa[(k + 2) * CDIM + c];
            s3 += (double)Wq[r * CDIM + k + 3] * (double)Wa[(k + 3) * CDIM + c];
        }
        pre[r * CDIM + c] = (float)(((s0 + s1) + (s2 + s3)) * LOG2E);
    } else if (r < 6) {
        const int rr = r - 3;
        double s0 = 0, s1 = 0, s2 = 0, s3 = 0;
        for (int k = 0; k < CDIM; k += 4) {
            s0 += (double)Wk[rr * CDIM + k + 0] * (double)Wa[(k + 0) * CDIM + c];
            s1 += (double)Wk[rr * CDIM + k + 1] * (double)Wa[(k + 1) * CDIM + c];
            s2 += (double)Wk[rr * CDIM + k + 2] * (double)Wa[(k + 2) * CDIM + c];
            s3 += (double)Wk[rr * CDIM + k + 3] * (double)Wa[(k + 3) * CDIM + c];
        }
        pre[r * CDIM + c] = (float)(((s0 + s1) + (s2 + s3)) * (-LOG2E));  // negated
    } else {
        double s = (double)ba[c];
        for (int k = 0; k < CDIM; ++k)
            s += ((double)bq[k] - (double)bk[k]) * (double)Wa[k * CDIM + c];
        pre[6 * CDIM + c] = (float)(s * LOG2E);
    }
}

// ---------------------------------------------------------------------------
// R10 parallel setup — ONE dispatch, 69 blocks x 256 (all co-resident).
// ---------------------------------------------------------------------------
#define SETUP_BLOCKS 69

__launch_bounds__(256)
__global__ void setup2_kernel(const float* __restrict__ neighbor,
                              const float* __restrict__ Wq, const float* __restrict__ bq,
                              const float* __restrict__ Wk, const float* __restrict__ bk,
                              const float* __restrict__ Wa, const float* __restrict__ ba,
                              float* __restrict__ pre,
                              int* __restrict__ starts,
                              int* __restrict__ cnts_blk,
                              int* __restrict__ ready,
                              int* __restrict__ go,
                              int* __restrict__ curs,
                              float4* __restrict__ pts4) {
    const int blk = blockIdx.x;
    const int t = threadIdx.x;

    if (blk < 64) {
        // ---- count phase ----
        __shared__ int hist[NCELL];
        __shared__ int base_sh[NCELL];
        const int b = blk >> 4;
        const int i = ((blk & 15) << 8) + t;          // 256 points per block
        if (t < NCELL) hist[t] = 0;
        __syncthreads();
        const float* p = neighbor + ((size_t)b * MDIM + i) * 3;
        const float x = p[0], y = p[1], z = p[2];
        const int cell = (cell_of(z) * 4 + cell_of(y)) * 4 + cell_of(x);
        const int myrank = atomicAdd(&hist[cell], 1);  // per-block per-cell rank
        __syncthreads();
        if (t < NCELL)
            __hip_atomic_store(&cnts_blk[blk * NCELL + t], hist[t],
                               __ATOMIC_RELAXED, __HIP_MEMORY_SCOPE_AGENT);
        __syncthreads();   // all publishes done (waitcnt) before flag
        if (t == 0)
            __hip_atomic_store(&ready[blk], MAGIC_RDY,
                               __ATOMIC_RELEASE, __HIP_MEMORY_SCOPE_AGENT);
        // ---- wait for scan ----
        if (t == 0) {
            while (__hip_atomic_load(go, __ATOMIC_ACQUIRE,
                                     __HIP_MEMORY_SCOPE_AGENT) != MAGIC_GO)
                __builtin_amdgcn_s_sleep(8);
        }
        __syncthreads();
        // ---- scatter phase: block-level reservation then ordered fill ----
        if (t < NCELL) {
            const int h = hist[t];
            base_sh[t] = h ? atomicAdd(&curs[b * NCELL + t], h) : 0;
        }
        __syncthreads();
        const int slot = base_sh[cell] + myrank;
        pts4[(size_t)b * MDIM + slot] = make_float4(x, y, z, __int_as_float(i));
    } else if (blk < 68) {
        // ---- fold phase on 4 CUs ----
        const int idx = (blk - 64) * 256 + t;
        if (idx < 7 * CDIM) fold_one(idx, Wq, bq, Wk, bk, Wa, ba, pre);
    } else {
        // ---- scan block ----
        const int lane = t & 63;
        if (t < 64) {   // wave 0: poll all 64 ready flags, one per lane
            while (!__all(__hip_atomic_load(&ready[lane], __ATOMIC_ACQUIRE,
                                            __HIP_MEMORY_SCOPE_AGENT) == MAGIC_RDY))
                __builtin_amdgcn_s_sleep(8);
        }
        __syncthreads();
        const int b = t >> 6;           // wave w handles batch w
        int v = 0;
        #pragma unroll
        for (int j = 0; j < 16; ++j)
            v += __hip_atomic_load(&cnts_blk[(b * 16 + j) * NCELL + lane],
                                   __ATOMIC_RELAXED, __HIP_MEMORY_SCOPE_AGENT);
        int inc = v;
        #pragma unroll
        for (int off = 1; off < 64; off <<= 1) {
            const int u = __shfl_up(inc, off);
            if (lane >= off) inc += u;
        }
        const int excl = inc - v;
        starts[b * (NCELL + 1) + lane] = excl;            // consumed post-boundary
        if (lane == NCELL - 1) starts[b * (NCELL + 1) + NCELL] = inc;
        __hip_atomic_store(&curs[b * NCELL + lane], excl,
                           __ATOMIC_RELAXED, __HIP_MEMORY_SCOPE_AGENT);
        __syncthreads();   // all curs stores complete
        if (t == 0)
            __hip_atomic_store(go, MAGIC_GO,
                               __ATOMIC_RELEASE, __HIP_MEMORY_SCOPE_AGENT);
    }
}

// ---------------------------------------------------------------------------
// Legacy fold-only setup — kept for the small-ws fallback path.
// ---------------------------------------------------------------------------
__launch_bounds__(1024)
__global__ void setup_kernel(const float* __restrict__ Wq, const float* __restrict__ bq,
                             const float* __restrict__ Wk, const float* __restrict__ bk,
                             const float* __restrict__ Wa, const float* __restrict__ ba,
                             float* __restrict__ pre) {
    const int t = threadIdx.x;
    if (t < 7 * CDIM) fold_one(t, Wq, bq, Wk, bk, Wa, ba, pre);
}

// ---------------------------------------------------------------------------
// Main kernel: 1 wave per anchor, WPB=2 waves / 128-thread block.
// R13: phase-2 reduction reverted to the proven builtin update_dpp form
//      (bit-identical to the R5 passing run); WPB=2 kept to measure the
//      imbalance/backfill hypothesis cleanly.
// ---------------------------------------------------------------------------
__launch_bounds__(64 * WPB)
__global__ void attn2_kernel(const float* __restrict__ anchor,
                             const float* __restrict__ neighbor,
                             const float* __restrict__ Wd,
                             const float* __restrict__ bd,
                             const float* __restrict__ pre,
                             const float4* __restrict__ pts4,
                             const int* __restrict__ starts,
                             float* __restrict__ out) {
    __shared__ float4 cand[WPB][CAP - KSEL];
    __shared__ float4 sel[WPB][KSEL];

    const int b    = blockIdx.x >> 11;             // 2048 blocks per batch
    const int n0   = (blockIdx.x & 2047) << 1;     // 2 anchors per block
    const int tid  = threadIdx.x;
    const int w    = tid >> 6;
    const int lane = tid & 63;

    const int n = n0 + w;
    const float* ap = anchor + ((size_t)b * NDIM + n) * 3;
    const float ax = ap[0], ay = ap[1], az = ap[2];
    const float* nbb = neighbor + (size_t)b * MDIM * 3;

    LaneW P;
    load_lane_weights(P, pre, Wd, bd, lane);

    const v2f axv = splat(ax), ayv = splat(ay), azv = splat(az);
    const v2f qa  = pk_fma(axv, P.wqa0, pk_fma(ayv, P.wqa1, pk_fma(azv, P.wqa2, P.cav)));
    const v2f ad  = pk_fma(axv, P.wd0, pk_fma(ayv, P.wd1, pk_fma(azv, P.wd2, P.bdv)));
    const v2f nad = -ad;   // phase 2 computes m = p·Wd − ad = −dis

    // --- phase 1: binned candidate collection ---
    constexpr float R2 = (float)(0.12 * 0.12);
    const float RP = 0.1201f;   // widened; 2*RP < 0.25 => <=2 cells/dim always

    const int cx0 = max(0, (int)((ax - RP) * 4.0f)), cx1 = min(3, (int)((ax + RP) * 4.0f));
    const int cy0 = max(0, (int)((ay - RP) * 4.0f)), cy1 = min(3, (int)((ay + RP) * 4.0f));
    const int cz0 = max(0, (int)((az - RP) * 4.0f)), cz1 = min(3, (int)((az + RP) * 4.0f));

    const float4* pb = pts4 + (size_t)b * MDIM;
    const int* st = starts + b * (NCELL + 1);

    // static 2x2 row enumeration (span <= 2 cells/dim always); all 8 loads
    // issue in parallel, duplicate rows are emptied via re=rs.
    const int r00 = (cz0 * 4 + cy0) * 4, r01 = (cz0 * 4 + cy1) * 4;
    const int r10 = (cz1 * 4 + cy0) * 4, r11 = (cz1 * 4 + cy1) * 4;
    int rs0 = st[r00 + cx0], re0 = st[r00 + cx1 + 1];
    int rs1 = st[r01 + cx0], re1 = st[r01 + cx1 + 1];
    int rs2 = st[r10 + cx0], re2 = st[r10 + cx1 + 1];
    int rs3 = st[r11 + cx0], re3 = st[r11 + cx1 + 1];
    const bool vy = cy1 > cy0, vz = cz1 > cz0;
    if (!vy) re1 = rs1;                       // row01 duplicates row00
    if (!vz) { re2 = rs2; re3 = rs3; }        // row1x duplicate row0x
    else if (!vy) re3 = rs3;                  // row11 duplicates row10

    int cnt = 0;
    auto scan_range = [&](int beg, int end) {
        if (beg >= end) return;
        float4 p = pb[min(beg + lane, end - 1)];
        for (int base = beg; base < end; base += 64) {
            // branchless prefetch of the next tile (clamped; harmless dup read
            // on the last iteration).
            float4 pn = pb[min(base + 64 + lane, end - 1)];
            const int i = base + lane;
            const float dx = __fsub_rn(ax, p.x);
            const float dy = __fsub_rn(ay, p.y);
            const float dz = __fsub_rn(az, p.z);
            const float d2 = __fadd_rn(__fadd_rn(__fmul_rn(dx, dx), __fmul_rn(dy, dy)),
                                       __fmul_rn(dz, dz));
            const bool in = (i < end) && (d2 < R2);
            const unsigned long long mk = __ballot(in);
            const int pos = cnt + rank_before(mk);
            if (in && pos < CAP) {
                if (pos < KSEL) sel[w][pos] = p;
                else            cand[w][pos - KSEL] = p;
            }
            cnt += __popcll(mk);
            p = pn;
        }
    };
    scan_range(rs0, re0);
    scan_range(rs1, re1);
    scan_range(rs2, re2);
    scan_range(rs3, re3);

    // --- selection: the K smallest original indices among hits ---
    int eff;
    if (cnt == 0) {
        if (lane == 0) sel[w][0] = make_float4(nbb[0], nbb[1], nbb[2], 0.0f);
        eff = 1;
    } else if (cnt <= KSEL) {
        eff = cnt;                       // sel already holds them, in hit order
    } else if (cnt <= CAP) {
        // gather hit h for this lane: h<KSEL -> sel[h], else cand[h-KSEL]
        float4 c0v = make_float4(0, 0, 0, 0), c1v = make_float4(0, 0, 0, 0);
        int i0 = 0x7fffffff, i1 = 0x7fffffff;
        if (lane < cnt) {
            c0v = (lane < KSEL) ? sel[w][lane] : cand[w][lane - KSEL];
            i0 = __float_as_int(c0v.w);
        }
        if (lane + 64 < cnt) {
            c1v = cand[w][lane + 64 - KSEL];
            i1 = __float_as_int(c1v.w);
        }
        int lo = 0, hi = MDIM - 1;   // smallest T with count(idx<=T) >= KSEL
        while (lo < hi) {
            const int mid = (lo + hi) >> 1;
            const int c = __popcll(__ballot(i0 <= mid)) + __popcll(__ballot(i1 <= mid));
            if (c >= KSEL) hi = mid; else lo = mid + 1;
        }
        __builtin_amdgcn_wave_barrier();   // reads above complete before sel rewrite
        const bool k0 = (i0 <= lo);
        const unsigned long long m0 = __ballot(k0);
        if (k0) sel[w][rank_before(m0)] = c0v;
        const int cc0 = __popcll(m0);
        const bool k1 = (i1 <= lo);
        const unsigned long long m1 = __ballot(k1);
        if (k1) sel[w][cc0 + rank_before(m1)] = c1v;
        eff = KSEL;
    } else {
        // overflow fallback (statistically never): ordered full scan, first K
        int c2 = 0;
        for (int base = 0; base < MDIM && c2 < KSEL; base += 64) {
            const int m = base + lane;
            const float* p = nbb + 3 * m;
            const float nx = p[0], ny = p[1], nz = p[2];
            const float dx = __fsub_rn(ax, nx);
            const float dy = __fsub_rn(ay, ny);
            const float dz = __fsub_rn(az, nz);
            const float d2 = __fadd_rn(__fadd_rn(__fmul_rn(dx, dx), __fmul_rn(dy, dy)),
                                       __fmul_rn(dz, dz));
            const bool in = d2 < R2;
            const unsigned long long mk = __ballot(in);
            const int pos = c2 + rank_before(mk);
            if (in && pos < KSEL) sel[w][pos] = make_float4(nx, ny, nz, 0.0f);
            c2 += __popcll(mk);
        }
        eff = KSEL;
    }

    __builtin_amdgcn_wave_barrier();
    __builtin_amdgcn_s_waitcnt(0);   // sel writes visible to this wave's reads

    // --- phase 2: packed channel softmax (exp2 domain) + min-accumulate of
    //     m·e/S where m = −dis; output negated at the store. Bulk groups of 8
    //     (no clamp), then one clamped tail group of 4 or 8 (dup of last
    //     point: idempotent under min, same denominator). ---
    v2f acc = splat(1e30f);

    auto group = [&](int j, int G, bool clamp) {
        v2f pr[8];
        float sv[8];
        #pragma unroll
        for (int t = 0; t < G; ++t) {
            const int idx = clamp ? min(j + t, eff - 1) : (j + t);
            const float4 v = sel[w][idx];
            const v2f vx = splat(v.x), vy2 = splat(v.y), vz2 = splat(v.z);
            const v2f l = pk_fma(vx, P.nka0, pk_fma(vy2, P.nka1, pk_fma(vz2, P.nka2, qa)));
            v2f e; e.x = exp2_hw(l.x); e.y = exp2_hw(l.y);
            sv[t] = e.x + e.y;
            const v2f m = pk_fma(vx, P.wd0, pk_fma(vy2, P.wd1, pk_fma(vz2, P.wd2, nad)));
            pr[t] = m * e;   // v_pk_mul_f32 (= −dis·e)
        }
        #pragma unroll
        for (int t = 0; t < G; ++t) sv[t] = dpp_add<DPP_QUAD_XOR1, 0xF>(sv[t]);
        #pragma unroll
        for (int t = 0; t < G; ++t) sv[t] = dpp_add<DPP_QUAD_XOR2, 0xF>(sv[t]);
        #pragma unroll
        for (int t = 0; t < G; ++t) sv[t] = dpp_add<DPP_ROW_HALF_MIRROR, 0xF>(sv[t]);
        #pragma unroll
        for (int t = 0; t < G; ++t) sv[t] = dpp_add<DPP_ROW_MIRROR, 0xF>(sv[t]);
        #pragma unroll
        for (int t = 0; t < G; ++t) sv[t] = dpp_add<DPP_ROW_BCAST15, 0xA>(sv[t]);
        #pragma unroll
        for (int t = 0; t < G; ++t) sv[t] = dpp_add<DPP_ROW_BCAST31, 0xC>(sv[t]);
        #pragma unroll
        for (int t = 0; t < G; ++t) {
            const float tot = __int_as_float(__builtin_amdgcn_readlane(__float_as_int(sv[t]), 63));
            const v2f iv = splat(__builtin_amdgcn_rcpf(tot));
            acc = __builtin_elementwise_min(acc, pr[t] * iv);   // pk_mul + pk_min
        }
    };

    int j = 0;
    for (; j + 8 <= eff; j += 8) group(j, 8, false);
    const int rem = eff - j;
    if (rem > 0) {
        if (rem <= 4) group(j, 4, true);
        else          group(j, 8, true);
    }

    float2 o; o.x = -acc.x; o.y = -acc.y;
    ((float2*)out)[((size_t)b * NDIM + n) * 64 + lane] = o;
}

// ---------------------------------------------------------------------------
// Fallback (ws too small for bins): full-scan kernel (ordered early-exit).
// ---------------------------------------------------------------------------
__launch_bounds__(256)
__global__ void attn_fallback(const float* __restrict__ anchor,
                              const float* __restrict__ neighbor,
                              const float* __restrict__ Wd,
                              const float* __restrict__ bd,
                              const float* __restrict__ pre,
                              float* __restrict__ out) {
    __shared__ float4 sel[4][KSEL];
    __shared__ int lists[4][KSEL];

    const int b = blockIdx.x >> 10, n0 = (blockIdx.x & 1023) << 2;
    const int tid = threadIdx.x, w = tid >> 6, lane = tid & 63;
    const int n = n0 + w;
    const float* ap = anchor + ((size_t)b * NDIM + n) * 3;
    const float ax = ap[0], ay = ap[1], az = ap[2];
    const float* nbb = neighbor + (size_t)b * MDIM * 3;

    LaneW P;
    load_lane_weights(P, pre, Wd, bd, lane);
    const v2f axv = splat(ax), ayv = splat(ay), azv = splat(az);
    const v2f qa = pk_fma(axv, P.wqa0, pk_fma(ayv, P.wqa1, pk_fma(azv, P.wqa2, P.cav)));
    const v2f ad = pk_fma(axv, P.wd0, pk_fma(ayv, P.wd1, pk_fma(azv, P.wd2, P.bdv)));
    const v2f nwd0 = -P.wd0, nwd1 = -P.wd1, nwd2 = -P.wd2;

    constexpr float R2 = (float)(0.12 * 0.12);
    int cnt = 0;
    for (int base = 0; base < MDIM && cnt < KSEL; base += 64) {
        const int m = base + lane;
        const float* p = nbb + 3 * m;
        const float dx = __fsub_rn(ax, p[0]);
        const float dy = __fsub_rn(ay, p[1]);
        const float dz = __fsub_rn(az, p[2]);
        const float d2 = __fadd_rn(__fadd_rn(__fmul_rn(dx, dx), __fmul_rn(dy, dy)),
                                   __fmul_rn(dz, dz));
        const bool in = d2 < R2;
        const unsigned long long mk = __ballot(in);
        const int pos = cnt + rank_before(mk);
        if (in && pos < KSEL) lists[w][pos] = m;
        cnt += __popcll(mk);
    }
    int eff = cnt < KSEL ? cnt : KSEL;
    if (cnt == 0) { if (lane == 0) lists[w][0] = 0; eff = 1; }
    const int eff4 = (eff + 3) & ~3;
    if (lane == 0) for (int j = eff; j < eff4; ++j) lists[w][j] = lists[w][0];
    __builtin_amdgcn_wave_barrier();
    if (lane < eff4) {
        const float* p = nbb + 3 * lists[w][lane];
        sel[w][lane] = make_float4(p[0], p[1], p[2], 0.f);
    }
    __builtin_amdgcn_wave_barrier();

    v2f acc = splat(-1e30f);
    for (int j = 0; j < eff4; j += 4) {
        v2f pr[4]; float sv[4];
        #pragma unroll
        for (int t = 0; t < 4; ++t) {
            const float4 v = sel[w][j + t];
            const v2f vx = splat(v.x), vy = splat(v.y), vz = splat(v.z);
            const v2f l = pk_fma(vx, P.nka0, pk_fma(vy, P.nka1, pk_fma(vz, P.nka2, qa)));
            v2f e; e.x = exp2_hw(l.x); e.y = exp2_hw(l.y);
            sv[t] = e.x + e.y;
            const v2f d = pk_fma(vx, nwd0, pk_fma(vy, nwd1, pk_fma(vz, nwd2, ad)));
            pr[t] = d * e;
        }
        #pragma unroll
        for (int t = 0; t < 4; ++t) sv[t] = dpp_add<DPP_QUAD_XOR1, 0xF>(sv[t]);
        #pragma unroll
        for (int t = 0; t < 4; ++t) sv[t] = dpp_add<DPP_QUAD_XOR2, 0xF>(sv[t]);
        #pragma unroll
        for (int t = 0; t < 4; ++t) sv[t] = dpp_add<DPP_ROW_HALF_MIRROR, 0xF>(sv[t]);
        #pragma unroll
        for (int t = 0; t < 4; ++t) sv[t] = dpp_add<DPP_ROW_MIRROR, 0xF>(sv[t]);
        #pragma unroll
        for (int t = 0; t < 4; ++t) sv[t] = dpp_add<DPP_ROW_BCAST15, 0xA>(sv[t]);
        #pragma unroll
        for (int t = 0; t < 4; ++t) sv[t] = dpp_add<DPP_ROW_BCAST31, 0xC>(sv[t]);
        #pragma unroll
        for (int t = 0; t < 4; ++t) {
            const float tot = __int_as_float(__builtin_amdgcn_readlane(__float_as_int(sv[t]), 63));
            const v2f iv = splat(__builtin_amdgcn_rcpf(tot));
            acc = __builtin_elementwise_max(acc, pr[t] * iv);
        }
    }
    float2 o; o.x = acc.x; o.y = acc.y;
    ((float2*)out)[((size_t)b * NDIM + n) * 64 + lane] = o;
}

extern "C" void kernel_launch(void* const* d_in, const int* in_sizes, int n_in,
                              void* d_out, int out_size, void* d_ws, size_t ws_size,
                              hipStream_t stream) {
    const float* anchor   = (const float*)d_in[0];
    const float* neighbor = (const float*)d_in[1];
    const float* Wq = (const float*)d_in[2];
    const float* bq = (const float*)d_in[3];
    const float* Wk = (const float*)d_in[4];
    const float* bk = (const float*)d_in[5];
    const float* Wd = (const float*)d_in[6];
    const float* bd = (const float*)d_in[7];
    const float* Wa = (const float*)d_in[8];
    const float* ba = (const float*)d_in[9];
    float* out = (float*)d_out;

    float* pre    = (float*)d_ws;
    int* starts   = (int*)((char*)d_ws + STARTS_OFF);
    int* cnts_blk = (int*)((char*)d_ws + CNTSB_OFF);
    int* ready    = (int*)((char*)d_ws + READY_OFF);
    int* go       = (int*)((char*)d_ws + GO_OFF);
    int* curs     = (int*)((char*)d_ws + CURS_OFF);
    float4* pts4  = (float4*)((char*)d_ws + PTS4_OFF);

    if (ws_size >= WS_NEEDED) {
        setup2_kernel<<<dim3(SETUP_BLOCKS), dim3(256), 0, stream>>>(
            neighbor, Wq, bq, Wk, bk, Wa, ba, pre, starts,
            cnts_blk, ready, go, curs, pts4);
        attn2_kernel<<<dim3(BDIM * NDIM / WPB), dim3(64 * WPB), 0, stream>>>(
            anchor, neighbor, Wd, bd, pre, pts4, starts, out);
    } else {
        setup_kernel<<<dim3(1), dim3(1024), 0, stream>>>(
            Wq, bq, Wk, bk, Wa, ba, pre);
        attn_fallback<<<dim3(BDIM * NDIM / 4), dim3(256), 0, stream>>>(
            anchor, neighbor, Wd, bd, pre, out);
    }
}

// Round 9
// 110.376 us; speedup vs baseline: 1.0299x; 1.0192x over previous
//
#include <hip/hip_runtime.h>
#include <math.h>

#define BDIM 4
#define NDIM 4096
#define MDIM 4096
#define CDIM 128
#define KSEL 32
#define NCELL 64     // 4x4x4 grid, cell 0.25 >= 2*r widened => ball spans <=2 cells/dim
#define CAP 128      // per-wave candidate cap (expected ~30 hits; P(>128) ~ 0)
#define WPB 2        // 128-thread blocks (R13-proven best-of-equals)

typedef float v2f __attribute__((ext_vector_type(2)));

// ws layout:
//   pre[7*C] f32        @ 0
//   starts[65*B] i32    @ STARTS_OFF
//   cnts_blk[64*64] i32 @ CNTSB_OFF   (per count-block histograms)
//   ready[64] i32       @ READY_OFF
//   go i32 (+pad)       @ GO_OFF
//   curs[B*64] i32      @ CURS_OFF
//   pts4[B*M] float4    @ PTS4_OFF
#define PRE_BYTES (7 * CDIM * 4)                        // 3584
#define STARTS_OFF PRE_BYTES
#define STARTS_BYTES ((NCELL + 1) * BDIM * 4)           // 1040
#define CNTSB_OFF (STARTS_OFF + STARTS_BYTES)           // 4624
#define CNTSB_BYTES (64 * NCELL * 4)                    // 16384
#define READY_OFF (CNTSB_OFF + CNTSB_BYTES)             // 21008
#define READY_BYTES (64 * 4)                            // 256
#define GO_OFF (READY_OFF + READY_BYTES)                // 21264
#define GO_BYTES 16
#define CURS_OFF (GO_OFF + GO_BYTES)                    // 21280
#define CURS_BYTES (BDIM * NCELL * 4)                   // 1024
#define PTS4_OFF (CURS_OFF + CURS_BYTES)                // 22304 (16B aligned)
#define WS_NEEDED (PTS4_OFF + (size_t)BDIM * MDIM * 16)

// distinct-byte magics: cannot equal any repeated-byte poison fill pattern
#define MAGIC_RDY 0x3A7C19E5
#define MAGIC_GO  0x5D2B8F41

// ---------------------------------------------------------------------------
// helpers
// ---------------------------------------------------------------------------
__device__ __forceinline__ float exp2_hw(float x) {   // bare v_exp_f32 (~1 ulp)
    float r;
    asm("v_exp_f32 %0, %1" : "=v"(r) : "v"(x));
    return r;
}

// R14/R15: denominator butterfly on the DS pipe. ds_swizzle BitMode patterns
// (ISA doc wave-reduction recipe): xor k with and=0x1F, or=0 =>
// offset = (k<<10)|0x1F. Cross-half (lane^32) via ds_bpermute with a
// precomputed byte address. Each step = 1 DS op + 1 VALU add, and the full
// sum lands in EVERY lane (no readlane broadcast). Builtins => compiler-
// managed waitcnts (R12/R13 lesson: no hand-written cross-lane asm).
// R15 fix: pattern must be an immediate => template parameter.
template <int PATTERN>
__device__ __forceinline__ float swz_add(float x) {
    return x + __int_as_float(__builtin_amdgcn_ds_swizzle(__float_as_int(x), PATTERN));
}
#define SWZ_XOR1  0x041F
#define SWZ_XOR2  0x081F
#define SWZ_XOR4  0x101F
#define SWZ_XOR8  0x201F
#define SWZ_XOR16 0x401F

// legacy builtin-based DPP reduction (kept for the fallback kernel)
template <int CTRL, int MASK>
__device__ __forceinline__ float dpp_add(float x) {
    const int r = __builtin_amdgcn_update_dpp(0, __float_as_int(x), CTRL, MASK, 0xF, true);
    return x + __int_as_float(r);
}
#define DPP_QUAD_XOR1 0xB1
#define DPP_QUAD_XOR2 0x4E
#define DPP_ROW_HALF_MIRROR 0x141
#define DPP_ROW_MIRROR      0x140
#define DPP_ROW_BCAST15     0x142
#define DPP_ROW_BCAST31     0x143

// # set bits of mk in lanes strictly below this lane (v_mbcnt_lo+hi)
__device__ __forceinline__ int rank_before(unsigned long long mk) {
    return __builtin_amdgcn_mbcnt_hi((unsigned)(mk >> 32),
                                     __builtin_amdgcn_mbcnt_lo((unsigned)mk, 0));
}

__device__ __forceinline__ int cell_of(float v) {
    int c = (int)(v * 4.0f);
    return c < 0 ? 0 : (c > 3 ? 3 : c);
}

__device__ __forceinline__ v2f splat(float x) { v2f r; r.x = x; r.y = x; return r; }

// packed fma: lowers to v_pk_fma_f32 (full-rate, 2 fp32 FMA / inst)
__device__ __forceinline__ v2f pk_fma(v2f a, v2f b, v2f c) {
    return __builtin_elementwise_fma(a, b, c);
}

// per-lane channel-pair weights (2 channels per lane)
struct LaneW {
    v2f wqa0, wqa1, wqa2;   // (Wq@Wa)*log2e
    v2f nka0, nka1, nka2;   // -(Wk@Wa)*log2e  (pre-negated)
    v2f cav;                // ((bq-bk)@Wa+ba)*log2e
    v2f wd0, wd1, wd2, bdv; // raw Wd rows + bd
};

__device__ __forceinline__ void load_lane_weights(LaneW& P, const float* pre,
                                                  const float* Wd, const float* bd, int lane) {
    const v2f* pre2 = (const v2f*)pre;
    const v2f* wdp  = (const v2f*)Wd;
    const v2f* bdp  = (const v2f*)bd;
    P.wqa0 = pre2[0 * 64 + lane]; P.wqa1 = pre2[1 * 64 + lane]; P.wqa2 = pre2[2 * 64 + lane];
    P.nka0 = pre2[3 * 64 + lane]; P.nka1 = pre2[4 * 64 + lane]; P.nka2 = pre2[5 * 64 + lane];
    P.cav  = pre2[6 * 64 + lane];
    P.wd0 = wdp[0 * 64 + lane]; P.wd1 = wdp[1 * 64 + lane]; P.wd2 = wdp[2 * 64 + lane];
    P.bdv = bdp[lane];
}

// ---------------------------------------------------------------------------
// fp64 folded-weight fold, work item i in [0, 7*128)  (numerics unchanged)
// ---------------------------------------------------------------------------
__device__ __forceinline__ void fold_one(int i, const float* Wq, const float* bq,
                                         const float* Wk, const float* bk,
                                         const float* Wa, const float* ba,
                                         float* pre) {
    const double LOG2E = 1.4426950408889634074;
    const int r = i >> 7, c = i & (CDIM - 1);
    if (r < 3) {
        double s0 = 0, s1 = 0, s2 = 0, s3 = 0;
        for (int k = 0; k < CDIM; k += 4) {
            s0 += (double)Wq[r * CDIM + k + 0] * (double)Wa[(k + 0) * CDIM + c];
            s1 += (double)Wq[r * CDIM + k + 1] * (double)Wa[(k + 1) * CDIM + c];
            s2 += (double)Wq[r * CDIM + k + 2] * (double)Wa[(k + 2) * CDIM + c];
            s3 += (double)Wq[r * CDIM + k + 3] * (double)Wa[(k + 3) * CDIM + c];
        }
        pre[r * CDIM + c] = (float)(((s0 + s1) + (s2 + s3)) * LOG2E);
    } else if (r < 6) {
        const int rr = r - 3;
        double s0 = 0, s1 = 0, s2 = 0, s3 = 0;
        for (int k = 0; k < CDIM; k += 4) {
            s0 += (double)Wk[rr * CDIM + k + 0] * (double)Wa[(k + 0) * CDIM + c];
            s1 += (double)Wk[rr * CDIM + k + 1] * (double)Wa[(k + 1) * CDIM + c];
            s2 += (double)Wk[rr * CDIM + k + 2] * (double)Wa[(k + 2) * CDIM + c];
            s3 += (double)Wk[rr * CDIM + k + 3] * (double)Wa[(k + 3) * CDIM + c];
        }
        pre[r * CDIM + c] = (float)(((s0 + s1) + (s2 + s3)) * (-LOG2E));  // negated
    } else {
        double s = (double)ba[c];
        for (int k = 0; k < CDIM; ++k)
            s += ((double)bq[k] - (double)bk[k]) * (double)Wa[k * CDIM + c];
        pre[6 * CDIM + c] = (float)(s * LOG2E);
    }
}

// ---------------------------------------------------------------------------
// R10 parallel setup — ONE dispatch, 69 blocks x 256 (all co-resident).
// ---------------------------------------------------------------------------
#define SETUP_BLOCKS 69

__launch_bounds__(256)
__global__ void setup2_kernel(const float* __restrict__ neighbor,
                              const float* __restrict__ Wq, const float* __restrict__ bq,
                              const float* __restrict__ Wk, const float* __restrict__ bk,
                              const float* __restrict__ Wa, const float* __restrict__ ba,
                              float* __restrict__ pre,
                              int* __restrict__ starts,
                              int* __restrict__ cnts_blk,
                              int* __restrict__ ready,
                              int* __restrict__ go,
                              int* __restrict__ curs,
                              float4* __restrict__ pts4) {
    const int blk = blockIdx.x;
    const int t = threadIdx.x;

    if (blk < 64) {
        // ---- count phase ----
        __shared__ int hist[NCELL];
        __shared__ int base_sh[NCELL];
        const int b = blk >> 4;
        const int i = ((blk & 15) << 8) + t;          // 256 points per block
        if (t < NCELL) hist[t] = 0;
        __syncthreads();
        const float* p = neighbor + ((size_t)b * MDIM + i) * 3;
        const float x = p[0], y = p[1], z = p[2];
        const int cell = (cell_of(z) * 4 + cell_of(y)) * 4 + cell_of(x);
        const int myrank = atomicAdd(&hist[cell], 1);  // per-block per-cell rank
        __syncthreads();
        if (t < NCELL)
            __hip_atomic_store(&cnts_blk[blk * NCELL + t], hist[t],
                               __ATOMIC_RELAXED, __HIP_MEMORY_SCOPE_AGENT);
        __syncthreads();   // all publishes done (waitcnt) before flag
        if (t == 0)
            __hip_atomic_store(&ready[blk], MAGIC_RDY,
                               __ATOMIC_RELEASE, __HIP_MEMORY_SCOPE_AGENT);
        // ---- wait for scan ----
        if (t == 0) {
            while (__hip_atomic_load(go, __ATOMIC_ACQUIRE,
                                     __HIP_MEMORY_SCOPE_AGENT) != MAGIC_GO)
                __builtin_amdgcn_s_sleep(8);
        }
        __syncthreads();
        // ---- scatter phase: block-level reservation then ordered fill ----
        if (t < NCELL) {
            const int h = hist[t];
            base_sh[t] = h ? atomicAdd(&curs[b * NCELL + t], h) : 0;
        }
        __syncthreads();
        const int slot = base_sh[cell] + myrank;
        pts4[(size_t)b * MDIM + slot] = make_float4(x, y, z, __int_as_float(i));
    } else if (blk < 68) {
        // ---- fold phase on 4 CUs ----
        const int idx = (blk - 64) * 256 + t;
        if (idx < 7 * CDIM) fold_one(idx, Wq, bq, Wk, bk, Wa, ba, pre);
    } else {
        // ---- scan block ----
        const int lane = t & 63;
        if (t < 64) {   // wave 0: poll all 64 ready flags, one per lane
            while (!__all(__hip_atomic_load(&ready[lane], __ATOMIC_ACQUIRE,
                                            __HIP_MEMORY_SCOPE_AGENT) == MAGIC_RDY))
                __builtin_amdgcn_s_sleep(8);
        }
        __syncthreads();
        const int b = t >> 6;           // wave w handles batch w
        int v = 0;
        #pragma unroll
        for (int j = 0; j < 16; ++j)
            v += __hip_atomic_load(&cnts_blk[(b * 16 + j) * NCELL + lane],
                                   __ATOMIC_RELAXED, __HIP_MEMORY_SCOPE_AGENT);
        int inc = v;
        #pragma unroll
        for (int off = 1; off < 64; off <<= 1) {
            const int u = __shfl_up(inc, off);
            if (lane >= off) inc += u;
        }
        const int excl = inc - v;
        starts[b * (NCELL + 1) + lane] = excl;            // consumed post-boundary
        if (lane == NCELL - 1) starts[b * (NCELL + 1) + NCELL] = inc;
        __hip_atomic_store(&curs[b * NCELL + lane], excl,
                           __ATOMIC_RELAXED, __HIP_MEMORY_SCOPE_AGENT);
        __syncthreads();   // all curs stores complete
        if (t == 0)
            __hip_atomic_store(go, MAGIC_GO,
                               __ATOMIC_RELEASE, __HIP_MEMORY_SCOPE_AGENT);
    }
}

// ---------------------------------------------------------------------------
// Legacy fold-only setup — kept for the small-ws fallback path.
// ---------------------------------------------------------------------------
__launch_bounds__(1024)
__global__ void setup_kernel(const float* __restrict__ Wq, const float* __restrict__ bq,
                             const float* __restrict__ Wk, const float* __restrict__ bk,
                             const float* __restrict__ Wa, const float* __restrict__ ba,
                             float* __restrict__ pre) {
    const int t = threadIdx.x;
    if (t < 7 * CDIM) fold_one(t, Wq, bq, Wk, bk, Wa, ba, pre);
}

// ---------------------------------------------------------------------------
// Main kernel: 1 wave per anchor, WPB=2 waves / 128-thread block.
// R15 (= R14 + immediate-pattern fix): denominator reduction via ds_swizzle
// (DS pipe) + adds, cross-half via ds_bpermute; full sum in every lane =>
// no readlane. −7 VALU/point (~22% of phase-2) moved onto the idle DS pipe.
// Denominator reassociated (balanced butterfly) — positive-term sum, drift
// ≲1e-5 abs, well inside the 1.98e-4 threshold.
// ---------------------------------------------------------------------------
__launch_bounds__(64 * WPB)
__global__ void attn2_kernel(const float* __restrict__ anchor,
                             const float* __restrict__ neighbor,
                             const float* __restrict__ Wd,
                             const float* __restrict__ bd,
                             const float* __restrict__ pre,
                             const float4* __restrict__ pts4,
                             const int* __restrict__ starts,
                             float* __restrict__ out) {
    __shared__ float4 cand[WPB][CAP - KSEL];
    __shared__ float4 sel[WPB][KSEL];

    const int b    = blockIdx.x >> 11;             // 2048 blocks per batch
    const int n0   = (blockIdx.x & 2047) << 1;     // 2 anchors per block
    const int tid  = threadIdx.x;
    const int w    = tid >> 6;
    const int lane = tid & 63;

    const int n = n0 + w;
    const float* ap = anchor + ((size_t)b * NDIM + n) * 3;
    const float ax = ap[0], ay = ap[1], az = ap[2];
    const float* nbb = neighbor + (size_t)b * MDIM * 3;

    LaneW P;
    load_lane_weights(P, pre, Wd, bd, lane);

    const v2f axv = splat(ax), ayv = splat(ay), azv = splat(az);
    const v2f qa  = pk_fma(axv, P.wqa0, pk_fma(ayv, P.wqa1, pk_fma(azv, P.wqa2, P.cav)));
    const v2f ad  = pk_fma(axv, P.wd0, pk_fma(ayv, P.wd1, pk_fma(azv, P.wd2, P.bdv)));
    const v2f nad = -ad;   // phase 2 computes m = p·Wd − ad = −dis

    const int xaddr = (lane ^ 32) << 2;   // ds_bpermute byte addr, cross-half

    // --- phase 1: binned candidate collection ---
    constexpr float R2 = (float)(0.12 * 0.12);
    const float RP = 0.1201f;   // widened; 2*RP < 0.25 => <=2 cells/dim always

    const int cx0 = max(0, (int)((ax - RP) * 4.0f)), cx1 = min(3, (int)((ax + RP) * 4.0f));
    const int cy0 = max(0, (int)((ay - RP) * 4.0f)), cy1 = min(3, (int)((ay + RP) * 4.0f));
    const int cz0 = max(0, (int)((az - RP) * 4.0f)), cz1 = min(3, (int)((az + RP) * 4.0f));

    const float4* pb = pts4 + (size_t)b * MDIM;
    const int* st = starts + b * (NCELL + 1);

    // static 2x2 row enumeration (span <= 2 cells/dim always); all 8 loads
    // issue in parallel, duplicate rows are emptied via re=rs.
    const int r00 = (cz0 * 4 + cy0) * 4, r01 = (cz0 * 4 + cy1) * 4;
    const int r10 = (cz1 * 4 + cy0) * 4, r11 = (cz1 * 4 + cy1) * 4;
    int rs0 = st[r00 + cx0], re0 = st[r00 + cx1 + 1];
    int rs1 = st[r01 + cx0], re1 = st[r01 + cx1 + 1];
    int rs2 = st[r10 + cx0], re2 = st[r10 + cx1 + 1];
    int rs3 = st[r11 + cx0], re3 = st[r11 + cx1 + 1];
    const bool vy = cy1 > cy0, vz = cz1 > cz0;
    if (!vy) re1 = rs1;                       // row01 duplicates row00
    if (!vz) { re2 = rs2; re3 = rs3; }        // row1x duplicate row0x
    else if (!vy) re3 = rs3;                  // row11 duplicates row10

    int cnt = 0;
    auto scan_range = [&](int beg, int end) {
        if (beg >= end) return;
        float4 p = pb[min(beg + lane, end - 1)];
        for (int base = beg; base < end; base += 64) {
            // branchless prefetch of the next tile (clamped; harmless dup read
            // on the last iteration).
            float4 pn = pb[min(base + 64 + lane, end - 1)];
            const int i = base + lane;
            const float dx = __fsub_rn(ax, p.x);
            const float dy = __fsub_rn(ay, p.y);
            const float dz = __fsub_rn(az, p.z);
            const float d2 = __fadd_rn(__fadd_rn(__fmul_rn(dx, dx), __fmul_rn(dy, dy)),
                                       __fmul_rn(dz, dz));
            const bool in = (i < end) && (d2 < R2);
            const unsigned long long mk = __ballot(in);
            const int pos = cnt + rank_before(mk);
            if (in && pos < CAP) {
                if (pos < KSEL) sel[w][pos] = p;
                else            cand[w][pos - KSEL] = p;
            }
            cnt += __popcll(mk);
            p = pn;
        }
    };
    scan_range(rs0, re0);
    scan_range(rs1, re1);
    scan_range(rs2, re2);
    scan_range(rs3, re3);

    // --- selection: the K smallest original indices among hits ---
    int eff;
    if (cnt == 0) {
        if (lane == 0) sel[w][0] = make_float4(nbb[0], nbb[1], nbb[2], 0.0f);
        eff = 1;
    } else if (cnt <= KSEL) {
        eff = cnt;                       // sel already holds them, in hit order
    } else if (cnt <= CAP) {
        // gather hit h for this lane: h<KSEL -> sel[h], else cand[h-KSEL]
        float4 c0v = make_float4(0, 0, 0, 0), c1v = make_float4(0, 0, 0, 0);
        int i0 = 0x7fffffff, i1 = 0x7fffffff;
        if (lane < cnt) {
            c0v = (lane < KSEL) ? sel[w][lane] : cand[w][lane - KSEL];
            i0 = __float_as_int(c0v.w);
        }
        if (lane + 64 < cnt) {
            c1v = cand[w][lane + 64 - KSEL];
            i1 = __float_as_int(c1v.w);
        }
        int lo = 0, hi = MDIM - 1;   // smallest T with count(idx<=T) >= KSEL
        while (lo < hi) {
            const int mid = (lo + hi) >> 1;
            const int c = __popcll(__ballot(i0 <= mid)) + __popcll(__ballot(i1 <= mid));
            if (c >= KSEL) hi = mid; else lo = mid + 1;
        }
        __builtin_amdgcn_wave_barrier();   // reads above complete before sel rewrite
        const bool k0 = (i0 <= lo);
        const unsigned long long m0 = __ballot(k0);
        if (k0) sel[w][rank_before(m0)] = c0v;
        const int cc0 = __popcll(m0);
        const bool k1 = (i1 <= lo);
        const unsigned long long m1 = __ballot(k1);
        if (k1) sel[w][cc0 + rank_before(m1)] = c1v;
        eff = KSEL;
    } else {
        // overflow fallback (statistically never): ordered full scan, first K
        int c2 = 0;
        for (int base = 0; base < MDIM && c2 < KSEL; base += 64) {
            const int m = base + lane;
            const float* p = nbb + 3 * m;
            const float nx = p[0], ny = p[1], nz = p[2];
            const float dx = __fsub_rn(ax, nx);
            const float dy = __fsub_rn(ay, ny);
            const float dz = __fsub_rn(az, nz);
            const float d2 = __fadd_rn(__fadd_rn(__fmul_rn(dx, dx), __fmul_rn(dy, dy)),
                                       __fmul_rn(dz, dz));
            const bool in = d2 < R2;
            const unsigned long long mk = __ballot(in);
            const int pos = c2 + rank_before(mk);
            if (in && pos < KSEL) sel[w][pos] = make_float4(nx, ny, nz, 0.0f);
            c2 += __popcll(mk);
        }
        eff = KSEL;
    }

    __builtin_amdgcn_wave_barrier();
    __builtin_amdgcn_s_waitcnt(0);   // sel writes visible to this wave's reads

    // --- phase 2: packed channel softmax (exp2 domain) + min-accumulate of
    //     m·e/S where m = −dis; output negated at the store. Bulk groups of 8
    //     (no clamp), then one clamped tail group of 4 or 8 (dup of last
    //     point: idempotent under min, same denominator). ---
    v2f acc = splat(1e30f);

    auto group = [&](int j, int G, bool clamp) {
        v2f pr[8];
        float sv[8];
        #pragma unroll
        for (int t = 0; t < G; ++t) {
            const int idx = clamp ? min(j + t, eff - 1) : (j + t);
            const float4 v = sel[w][idx];
            const v2f vx = splat(v.x), vy2 = splat(v.y), vz2 = splat(v.z);
            const v2f l = pk_fma(vx, P.nka0, pk_fma(vy2, P.nka1, pk_fma(vz2, P.nka2, qa)));
            v2f e; e.x = exp2_hw(l.x); e.y = exp2_hw(l.y);
            sv[t] = e.x + e.y;
            const v2f m = pk_fma(vx, P.wd0, pk_fma(vy2, P.wd1, pk_fma(vz2, P.wd2, nad)));
            pr[t] = m * e;   // v_pk_mul_f32 (= −dis·e)
        }
        // DS-pipe butterfly: xor 1,2,4,8,16 within 32-lane halves, then
        // cross-half via bpermute. Full sum in every lane afterwards.
        #pragma unroll
        for (int t = 0; t < G; ++t) sv[t] = swz_add<SWZ_XOR1>(sv[t]);
        #pragma unroll
        for (int t = 0; t < G; ++t) sv[t] = swz_add<SWZ_XOR2>(sv[t]);
        #pragma unroll
        for (int t = 0; t < G; ++t) sv[t] = swz_add<SWZ_XOR4>(sv[t]);
        #pragma unroll
        for (int t = 0; t < G; ++t) sv[t] = swz_add<SWZ_XOR8>(sv[t]);
        #pragma unroll
        for (int t = 0; t < G; ++t) sv[t] = swz_add<SWZ_XOR16>(sv[t]);
        #pragma unroll
        for (int t = 0; t < G; ++t)
            sv[t] += __int_as_float(__builtin_amdgcn_ds_bpermute(xaddr, __float_as_int(sv[t])));
        #pragma unroll
        for (int t = 0; t < G; ++t) {
            const v2f iv = splat(__builtin_amdgcn_rcpf(sv[t]));
            acc = __builtin_elementwise_min(acc, pr[t] * iv);   // pk_mul + pk_min
        }
    };

    int j = 0;
    for (; j + 8 <= eff; j += 8) group(j, 8, false);
    const int rem = eff - j;
    if (rem > 0) {
        if (rem <= 4) group(j, 4, true);
        else          group(j, 8, true);
    }

    float2 o; o.x = -acc.x; o.y = -acc.y;
    ((float2*)out)[((size_t)b * NDIM + n) * 64 + lane] = o;
}

// ---------------------------------------------------------------------------
// Fallback (ws too small for bins): full-scan kernel (ordered early-exit).
// ---------------------------------------------------------------------------
__launch_bounds__(256)
__global__ void attn_fallback(const float* __restrict__ anchor,
                              const float* __restrict__ neighbor,
                              const float* __restrict__ Wd,
                              const float* __restrict__ bd,
                              const float* __restrict__ pre,
                              float* __restrict__ out) {
    __shared__ float4 sel[4][KSEL];
    __shared__ int lists[4][KSEL];

    const int b = blockIdx.x >> 10, n0 = (blockIdx.x & 1023) << 2;
    const int tid = threadIdx.x, w = tid >> 6, lane = tid & 63;
    const int n = n0 + w;
    const float* ap = anchor + ((size_t)b * NDIM + n) * 3;
    const float ax = ap[0], ay = ap[1], az = ap[2];
    const float* nbb = neighbor + (size_t)b * MDIM * 3;

    LaneW P;
    load_lane_weights(P, pre, Wd, bd, lane);
    const v2f axv = splat(ax), ayv = splat(ay), azv = splat(az);
    const v2f qa = pk_fma(axv, P.wqa0, pk_fma(ayv, P.wqa1, pk_fma(azv, P.wqa2, P.cav)));
    const v2f ad = pk_fma(axv, P.wd0, pk_fma(ayv, P.wd1, pk_fma(azv, P.wd2, P.bdv)));
    const v2f nwd0 = -P.wd0, nwd1 = -P.wd1, nwd2 = -P.wd2;

    constexpr float R2 = (float)(0.12 * 0.12);
    int cnt = 0;
    for (int base = 0; base < MDIM && cnt < KSEL; base += 64) {
        const int m = base + lane;
        const float* p = nbb + 3 * m;
        const float dx = __fsub_rn(ax, p[0]);
        const float dy = __fsub_rn(ay, p[1]);
        const float dz = __fsub_rn(az, p[2]);
        const float d2 = __fadd_rn(__fadd_rn(__fmul_rn(dx, dx), __fmul_rn(dy, dy)),
                                   __fmul_rn(dz, dz));
        const bool in = d2 < R2;
        const unsigned long long mk = __ballot(in);
        const int pos = cnt + rank_before(mk);
        if (in && pos < KSEL) lists[w][pos] = m;
        cnt += __popcll(mk);
    }
    int eff = cnt < KSEL ? cnt : KSEL;
    if (cnt == 0) { if (lane == 0) lists[w][0] = 0; eff = 1; }
    const int eff4 = (eff + 3) & ~3;
    if (lane == 0) for (int j = eff; j < eff4; ++j) lists[w][j] = lists[w][0];
    __builtin_amdgcn_wave_barrier();
    if (lane < eff4) {
        const float* p = nbb + 3 * lists[w][lane];
        sel[w][lane] = make_float4(p[0], p[1], p[2], 0.f);
    }
    __builtin_amdgcn_wave_barrier();

    v2f acc = splat(-1e30f);
    for (int j = 0; j < eff4; j += 4) {
        v2f pr[4]; float sv[4];
        #pragma unroll
        for (int t = 0; t < 4; ++t) {
            const float4 v = sel[w][j + t];
            const v2f vx = splat(v.x), vy = splat(v.y), vz = splat(v.z);
            const v2f l = pk_fma(vx, P.nka0, pk_fma(vy, P.nka1, pk_fma(vz, P.nka2, qa)));
            v2f e; e.x = exp2_hw(l.x); e.y = exp2_hw(l.y);
            sv[t] = e.x + e.y;
            const v2f d = pk_fma(vx, nwd0, pk_fma(vy, nwd1, pk_fma(vz, nwd2, ad)));
            pr[t] = d * e;
        }
        #pragma unroll
        for (int t = 0; t < 4; ++t) sv[t] = dpp_add<DPP_QUAD_XOR1, 0xF>(sv[t]);
        #pragma unroll
        for (int t = 0; t < 4; ++t) sv[t] = dpp_add<DPP_QUAD_XOR2, 0xF>(sv[t]);
        #pragma unroll
        for (int t = 0; t < 4; ++t) sv[t] = dpp_add<DPP_ROW_HALF_MIRROR, 0xF>(sv[t]);
        #pragma unroll
        for (int t = 0; t < 4; ++t) sv[t] = dpp_add<DPP_ROW_MIRROR, 0xF>(sv[t]);
        #pragma unroll
        for (int t = 0; t < 4; ++t) sv[t] = dpp_add<DPP_ROW_BCAST15, 0xA>(sv[t]);
        #pragma unroll
        for (int t = 0; t < 4; ++t) sv[t] = dpp_add<DPP_ROW_BCAST31, 0xC>(sv[t]);
        #pragma unroll
        for (int t = 0; t < 4; ++t) {
            const float tot = __int_as_float(__builtin_amdgcn_readlane(__float_as_int(sv[t]), 63));
            const v2f iv = splat(__builtin_amdgcn_rcpf(tot));
            acc = __builtin_elementwise_max(acc, pr[t] * iv);
        }
    }
    float2 o; o.x = acc.x; o.y = acc.y;
    ((float2*)out)[((size_t)b * NDIM + n) * 64 + lane] = o;
}

extern "C" void kernel_launch(void* const* d_in, const int* in_sizes, int n_in,
                              void* d_out, int out_size, void* d_ws, size_t ws_size,
                              hipStream_t stream) {
    const float* anchor   = (const float*)d_in[0];
    const float* neighbor = (const float*)d_in[1];
    const float* Wq = (const float*)d_in[2];
    const float* bq = (const float*)d_in[3];
    const float* Wk = (const float*)d_in[4];
    const float* bk = (const float*)d_in[5];
    const float* Wd = (const float*)d_in[6];
    const float* bd = (const float*)d_in[7];
    const float* Wa = (const float*)d_in[8];
    const float* ba = (const float*)d_in[9];
    float* out = (float*)d_out;

    float* pre    = (float*)d_ws;
    int* starts   = (int*)((char*)d_ws + STARTS_OFF);
    int* cnts_blk = (int*)((char*)d_ws + CNTSB_OFF);
    int* ready    = (int*)((char*)d_ws + READY_OFF);
    int* go       = (int*)((char*)d_ws + GO_OFF);
    int* curs     = (int*)((char*)d_ws + CURS_OFF);
    float4* pts4  = (float4*)((char*)d_ws + PTS4_OFF);

    if (ws_size >= WS_NEEDED) {
        setup2_kernel<<<dim3(SETUP_BLOCKS), dim3(256), 0, stream>>>(
            neighbor, Wq, bq, Wk, bk, Wa, ba, pre, starts,
            cnts_blk, ready, go, curs, pts4);
        attn2_kernel<<<dim3(BDIM * NDIM / WPB), dim3(64 * WPB), 0, stream>>>(
            anchor, neighbor, Wd, bd, pre, pts4, starts, out);
    } else {
        setup_kernel<<<dim3(1), dim3(1024), 0, stream>>>(
            Wq, bq, Wk, bk, Wa, ba, pre);
        attn_fallback<<<dim3(BDIM * NDIM / 4), dim3(256), 0, stream>>>(
            anchor, neighbor, Wd, bd, pre, out);
    }
}